// Round 3
// baseline (156.904 us; speedup 1.0000x reference)
//
#include <hip/hip_runtime.h>

#define NN 4096
#define DD 2048
#define MARGIN_F 0.3f
#define NTILES 528   // 128x128 tiles covering the upper triangle (nj >= mi)
#define BK 128       // K bytes per stage
#define NIT (DD / BK)  // 16
#define QS (127.0f / 6.0f)
#define C2 (2.0f * (6.0f / 127.0f) * (6.0f / 127.0f))  // 2/QS^2

typedef __attribute__((ext_vector_type(4))) int i32x4;

__device__ __forceinline__ unsigned q8(float v) {
    int i = __float2int_rn(v * QS);
    i = min(127, max(-127, i));
    return (unsigned)(i & 255);
}

// 1024 blocks x 4 waves; each wave quantizes one row (int8) + fp32
// sum-of-squares; init ap/an/counter.
__global__ __launch_bounds__(256) void prep_kernel(const float* __restrict__ x,
                                                   unsigned char* __restrict__ xq,
                                                   float* __restrict__ sq,
                                                   unsigned int* __restrict__ ap,
                                                   unsigned int* __restrict__ an,
                                                   int* __restrict__ counter) {
    const int wave = threadIdx.x >> 6, lane = threadIdx.x & 63;
    const int row = blockIdx.x * 4 + wave;
    const float* xr = x + (size_t)row * DD;
    unsigned int* orow = (unsigned int*)(xq + (size_t)row * DD);
    float s = 0.0f;
#pragma unroll
    for (int j = 0; j < 8; ++j) {
        float4 v = ((const float4*)xr)[j * 64 + lane];
        s += v.x * v.x + v.y * v.y + v.z * v.z + v.w * v.w;
        orow[j * 64 + lane] = q8(v.x) | (q8(v.y) << 8) | (q8(v.z) << 16) | (q8(v.w) << 24);
    }
    for (int off = 32; off > 0; off >>= 1) s += __shfl_down(s, off, 64);
    if (lane == 0) {
        sq[row] = s;
        ap[row] = 0u;            // hardest-positive max starts at 0
        an[row] = 0x7F800000u;   // +inf
    }
    if (threadIdx.x == 0 && blockIdx.x == 0) counter[0] = 0;
}

// Symmetric batch-hard GEMM, int8. R10 geometry: 128x128 tiles, 8 waves
// (512 thr), BK=128 double-buffered, counted vmcnt(4) (never 0 in-loop).
// Why: R2 post-mortem showed runtime = (seq blocks/CU) x NIT x
// per-phase-latency with only 8 waves/CU to hide misses. 128x128 halves
// NTILES (1056->528 = 8*66, bijective XCD swizzle intact), 64 KB LDS
// keeps 2 blocks/CU -> 16 waves/CU (50% occ, 2x workforce), and total
// staging traffic drops 415->276 MB. Per-wave phase content unchanged
// (16 MFMA, 12 ds_read_b128, conflict-free col^(row&7) swizzle, PMC=0).
// Wave grid 2x4: wave owns 64x32 sub-tile (4x2 frags).
// Both-side epilogues (idempotent max/min, gi!=gj guards diagonal);
// fused last-block finalize.
__global__ __launch_bounds__(512) void gemm_reduce_kernel(
    const unsigned char* __restrict__ xq,
    const float* __restrict__ sq,
    const int* __restrict__ labels,
    unsigned int* __restrict__ ap,
    unsigned int* __restrict__ an,
    int* __restrict__ counter,
    float* __restrict__ out) {
    __shared__ __align__(16) unsigned char As0[128 * BK];   // 16 KB
    __shared__ __align__(16) unsigned char Bs0[128 * BK];   // 16 KB
    __shared__ __align__(16) unsigned char As1[128 * BK];   // 16 KB
    __shared__ __align__(16) unsigned char Bs1[128 * BK];   // 16 KB

    // XCD-aware bijective swizzle: 528 = 8 * 66 exactly.
    const int orig = blockIdx.x;
    const int wgid = (orig & 7) * (NTILES / 8) + (orig >> 3);

    // decode tile: (mi, nj) upper triangle, nj >= mi, mi row-block of 128,
    // nj col-block of 128; count for a given mi is 32 - mi.
    int rem = wgid;
    int mi = 0;
    while (rem >= 32 - mi) { rem -= 32 - mi; ++mi; }
    const int nj = mi + rem;
    const int row0 = mi * 128;
    const int col0 = nj * 128;

    const int t = threadIdx.x;
    const int lane = t & 63;
    const int wave = t >> 6;           // 0..7
    const int c = lane & 15;           // fragment column lane
    const int q = lane >> 4;           // k-quad
    const int wrow = (wave >> 2) * 64; // wave row offset (2 row-halves)
    const int wcol = (wave & 3) * 32;  // wave col offset (4 col-quarters)

    i32x4 acc[4][2];
#pragma unroll
    for (int mm = 0; mm < 4; ++mm)
#pragma unroll
        for (int ni = 0; ni < 2; ++ni)
            acc[mm][ni] = (i32x4){0, 0, 0, 0};

    // Staging: rows are 128 B = 8 chunks of 16 B. Each tile (A or B) is
    // 128 rows = 1024 chunks; 512 threads -> 2 chunks/thread/tile.
    // Chunk ci = t + 512*s: row = ci>>3 = (t>>3) + 64*s, col = t&7;
    // source col XOR-swizzled: col ^ (row&7); row&7 = (t>>3)&7 is
    // s-invariant, so one swizzled col per thread.
    const int rowb = t >> 3;
    const int colsw = (t & 7) ^ (rowb & 7);
    const unsigned char* gA[2];
    const unsigned char* gB[2];
#pragma unroll
    for (int s = 0; s < 2; ++s) {
        gA[s] = xq + (size_t)(row0 + rowb + 64 * s) * DD + colsw * 16;
        gB[s] = xq + (size_t)(col0 + rowb + 64 * s) * DD + colsw * 16;
    }

    // 4 global_load_lds per thread per stage (per-wave vmcnt += 4).
    auto stage = [&](unsigned char* A, unsigned char* B, int it) {
        const int k0 = it * BK;
#pragma unroll
        for (int s = 0; s < 2; ++s)
            __builtin_amdgcn_global_load_lds(
                (const __attribute__((address_space(1))) void*)(gA[s] + k0),
                (__attribute__((address_space(3))) void*)&A[(t + 512 * s) * 16],
                16, 0, 0);
#pragma unroll
        for (int s = 0; s < 2; ++s)
            __builtin_amdgcn_global_load_lds(
                (const __attribute__((address_space(1))) void*)(gB[s] + k0),
                (__attribute__((address_space(3))) void*)&B[(t + 512 * s) * 16],
                16, 0, 0);
    };

    auto compute = [&](const unsigned char* A, const unsigned char* B) {
        const i32x4* Av = (const i32x4*)A;
        const i32x4* Bv = (const i32x4*)B;
#pragma unroll
        for (int ks = 0; ks < 2; ++ks) {
            const int kc = q + 4 * ks;  // k-chunk for this lane's fragment
            i32x4 af[4], bfr[2];
#pragma unroll
            for (int mm = 0; mm < 4; ++mm) {
                const int r = wrow + mm * 16 + c;
                af[mm] = Av[r * 8 + (kc ^ (r & 7))];
            }
#pragma unroll
            for (int ni = 0; ni < 2; ++ni) {
                const int r = wcol + ni * 16 + c;
                bfr[ni] = Bv[r * 8 + (kc ^ (r & 7))];
            }
#pragma unroll
            for (int mm = 0; mm < 4; ++mm)
#pragma unroll
                for (int ni = 0; ni < 2; ++ni)
                    acc[mm][ni] = __builtin_amdgcn_mfma_i32_16x16x64_i8(
                        af[mm], bfr[ni], acc[mm][ni], 0, 0, 0);
        }
    };

    // Counted-vmcnt pipeline. Ledger (per wave, 4 loads/stage):
    //   prologue: stage(0), stage(1)           -> 8 outstanding
    //   phase(it): vmcnt(4) waits stage(it) done (only stage(it+1)'s 4
    //   remain); s_barrier -> buf ready for all waves; compute; fence +
    //   s_barrier -> all waves done READING buf; re-stage buf for it+2.
    //   Last phase vmcnt(0) (nothing behind it). No drain elsewhere.
    stage(As0, Bs0, 0);
    stage(As1, Bs1, 1);
#pragma unroll
    for (int it = 0; it < NIT; it += 2) {
        // ---- phase A: tile it in {As0,Bs0} ----
        asm volatile("s_waitcnt vmcnt(4)" ::: "memory");
        __builtin_amdgcn_s_barrier();
        compute(As0, Bs0);
        asm volatile("" ::: "memory");  // keep ds_reads above the barrier
        __builtin_amdgcn_s_barrier();
        if (it + 2 < NIT) stage(As0, Bs0, it + 2);
        // ---- phase B: tile it+1 in {As1,Bs1} ----
        if (it + 2 < NIT)
            asm volatile("s_waitcnt vmcnt(4)" ::: "memory");
        else
            asm volatile("s_waitcnt vmcnt(0)" ::: "memory");
        __builtin_amdgcn_s_barrier();
        compute(As1, Bs1);
        asm volatile("" ::: "memory");
        __builtin_amdgcn_s_barrier();
        if (it + 3 < NIT) stage(As1, Bs1, it + 3);
    }

    // --- Epilogue ---
    // C/D layout 16x16: col = lane&15 (c), row = q*4 + reg [m89/m91;
    // dtype-independent m121-m128]
    float sq_col[2];
    int lab_col[2];
#pragma unroll
    for (int ni = 0; ni < 2; ++ni) {
        const int gj = col0 + wcol + ni * 16 + c;
        sq_col[ni] = sq[gj];
        lab_col[ni] = labels[gj];
    }
    int lab_row[4][4];
    float dist[4][2][4];
#pragma unroll
    for (int mm = 0; mm < 4; ++mm) {
#pragma unroll
        for (int r = 0; r < 4; ++r) {
            const int gi = row0 + wrow + mm * 16 + q * 4 + r;
            const float sqi = sq[gi];
            lab_row[mm][r] = labels[gi];
#pragma unroll
            for (int ni = 0; ni < 2; ++ni) {
                float d2 = sqi + sq_col[ni] - C2 * (float)acc[mm][ni][r];
                dist[mm][ni][r] = sqrtf(fmaxf(d2, 0.0f));
            }
        }
    }

    // Row-side: rows gi vs this wave's 32 columns.
#pragma unroll
    for (int mm = 0; mm < 4; ++mm) {
#pragma unroll
        for (int r = 0; r < 4; ++r) {
            const int gi = row0 + wrow + mm * 16 + q * 4 + r;
            const int li = lab_row[mm][r];
            float apm = 0.0f;
            float anm = __builtin_inff();
#pragma unroll
            for (int ni = 0; ni < 2; ++ni) {
                const int gj = col0 + wcol + ni * 16 + c;
                const float d = dist[mm][ni][r];
                if (li == lab_col[ni]) {
                    if (gi != gj) apm = fmaxf(apm, d);  // exclude diagonal
                } else {
                    anm = fminf(anm, d);
                }
            }
#pragma unroll
            for (int off = 1; off < 16; off <<= 1) {
                apm = fmaxf(apm, __shfl_xor(apm, off, 16));
                anm = fminf(anm, __shfl_xor(anm, off, 16));
            }
            if (c == 0) {
                atomicMax(&ap[gi], __float_as_uint(apm));
                atomicMin(&an[gi], __float_as_uint(anm));
            }
        }
    }

    // Column-side (transposed): S(gi,gj) also serves row gj (dupes
    // idempotent; diagonal guarded).
#pragma unroll
    for (int ni = 0; ni < 2; ++ni) {
        const int gj = col0 + wcol + ni * 16 + c;
        const int lj = lab_col[ni];
        float apm = 0.0f;
        float anm = __builtin_inff();
#pragma unroll
        for (int mm = 0; mm < 4; ++mm) {
#pragma unroll
            for (int r = 0; r < 4; ++r) {
                const int gi = row0 + wrow + mm * 16 + q * 4 + r;
                const float d = dist[mm][ni][r];
                if (lj == lab_row[mm][r]) {
                    if (gi != gj) apm = fmaxf(apm, d);  // exclude diagonal
                } else {
                    anm = fminf(anm, d);
                }
            }
        }
        apm = fmaxf(apm, __shfl_xor(apm, 16, 64));
        anm = fminf(anm, __shfl_xor(anm, 16, 64));
        apm = fmaxf(apm, __shfl_xor(apm, 32, 64));
        anm = fminf(anm, __shfl_xor(anm, 32, 64));
        if (q == 0) {
            atomicMax(&ap[gj], __float_as_uint(apm));
            atomicMin(&an[gj], __float_as_uint(anm));
        }
    }

    // --- Fused finalize: last block to finish reduces the loss ---
    __syncthreads();  // drains this block's atomics before counter release
    int* flag = (int*)As0;
    if (t == 0) {
        int old = __hip_atomic_fetch_add(counter, 1, __ATOMIC_ACQ_REL,
                                         __HIP_MEMORY_SCOPE_AGENT);
        flag[0] = (old == NTILES - 1) ? 1 : 0;
    }
    __syncthreads();
    if (flag[0]) {
        float sum = 0.0f;
        int cnt = 0;
        for (int i = t; i < NN; i += 512) {
            const float a = __uint_as_float(__hip_atomic_load(
                &ap[i], __ATOMIC_RELAXED, __HIP_MEMORY_SCOPE_AGENT));
            const float b = __uint_as_float(__hip_atomic_load(
                &an[i], __ATOMIC_RELAXED, __HIP_MEMORY_SCOPE_AGENT));
            if ((a > 0.0f) && (b < __builtin_inff())) {
                sum += fmaxf(a - b + MARGIN_F, 0.0f);
                cnt += 1;
            }
        }
        for (int off = 32; off > 0; off >>= 1) {
            sum += __shfl_down(sum, off, 64);
            cnt += __shfl_down(cnt, off, 64);
        }
        float* ssum = (float*)Bs0;
        int* scnt = (int*)Bs0 + 8;
        if (lane == 0) { ssum[wave] = sum; scnt[wave] = cnt; }
        __syncthreads();
        if (t == 0) {
            float s = 0.0f; int n = 0;
#pragma unroll
            for (int w = 0; w < 8; ++w) { s += ssum[w]; n += scnt[w]; }
            out[0] = (n > 0) ? s / (float)n : 0.0f;
        }
    }
}

extern "C" void kernel_launch(void* const* d_in, const int* in_sizes, int n_in,
                              void* d_out, int out_size, void* d_ws, size_t ws_size,
                              hipStream_t stream) {
    const float* x = (const float*)d_in[0];
    const int* labels = (const int*)d_in[1];
    float* out = (float*)d_out;

    char* ws = (char*)d_ws;
    unsigned char* xq = (unsigned char*)ws;                         // 4096*2048 B
    float* sq = (float*)(ws + (size_t)NN * DD);
    unsigned int* ap = (unsigned int*)(ws + (size_t)NN * DD + (size_t)NN * 4);
    unsigned int* an = (unsigned int*)(ws + (size_t)NN * DD + (size_t)NN * 8);
    int* counter = (int*)(ws + (size_t)NN * DD + (size_t)NN * 12);

    prep_kernel<<<NN / 4, 256, 0, stream>>>(x, xq, sq, ap, an, counter);
    gemm_reduce_kernel<<<NTILES, 512, 0, stream>>>(xq, sq, labels, ap, an, counter, out);
}

// Round 5
// 152.376 us; speedup vs baseline: 1.0297x; 1.0297x over previous
//
#include <hip/hip_runtime.h>

#define NN 4096
#define DD 2048
#define MARGIN_F 0.3f
#define NTILES 1056  // 64x128 tiles covering the upper triangle (dupes OK)
#define BK 256       // K bytes per stage
#define NIT (DD / BK)  // 8
#define QS (127.0f / 6.0f)
#define C2 (2.0f * (6.0f / 127.0f) * (6.0f / 127.0f))  // 2/QS^2

typedef __attribute__((ext_vector_type(4))) int i32x4;

__device__ __forceinline__ unsigned q8(float v) {
    int i = __float2int_rn(v * QS);
    i = min(127, max(-127, i));
    return (unsigned)(i & 255);
}

// 1024 blocks x 4 waves; each wave quantizes one row (int8) + fp32
// sum-of-squares; init ap/an/counter.
__global__ __launch_bounds__(256) void prep_kernel(const float* __restrict__ x,
                                                   unsigned char* __restrict__ xq,
                                                   float* __restrict__ sq,
                                                   unsigned int* __restrict__ ap,
                                                   unsigned int* __restrict__ an,
                                                   int* __restrict__ counter) {
    const int wave = threadIdx.x >> 6, lane = threadIdx.x & 63;
    const int row = blockIdx.x * 4 + wave;
    const float* xr = x + (size_t)row * DD;
    unsigned int* orow = (unsigned int*)(xq + (size_t)row * DD);
    float s = 0.0f;
#pragma unroll
    for (int j = 0; j < 8; ++j) {
        float4 v = ((const float4*)xr)[j * 64 + lane];
        s += v.x * v.x + v.y * v.y + v.z * v.z + v.w * v.w;
        orow[j * 64 + lane] = q8(v.x) | (q8(v.y) << 8) | (q8(v.z) << 16) | (q8(v.w) << 24);
    }
    for (int off = 32; off > 0; off >>= 1) s += __shfl_down(s, off, 64);
    if (lane == 0) {
        sq[row] = s;
        ap[row] = 0u;            // hardest-positive max starts at 0
        an[row] = 0x7F800000u;   // +inf
    }
    if (threadIdx.x == 0 && blockIdx.x == 0) counter[0] = 0;
}

// Symmetric batch-hard GEMM, int8. R12 = R0 (proven champion: 64x128
// tiles, BK=256, NIT=8, 48 KB LDS -> 3 blocks/CU, plain drain barriers)
// with exactly ONE mechanism changed: L2 locality.
//   (a) bijective XCD swizzle (1056 = 8*132): consecutive wgids share
//       the A row-panel and walk consecutive B panels -> per-XCD
//       per-phase working set ~0.9 MB << 4 MB L2 (R0-R3 measured
//       FETCH 38-67 MB vs 8 MB compulsory = 5x HBM re-fetch; the ~900cy
//       HBM misses are what the phases stall on).
//   (b) K-stagger REMOVED (stagger and XCD locality are mutually
//       exclusive: staggered co-residents touch all K-slices at once;
//       lock-step blocks read the same 256-B K-slice of few panels).
//       Int accumulation -> bitwise-identical result.
// Everything else is byte-identical to R0: 16-chunk rows with
// col' = col ^ (row&15) swizzle (2-way aliasing = free, PMC=0),
// mfma_i32_16x16x64_i8, wave = 64 rows x 32 cols (4x2 frags), 4
// k-chunks/stage. Both-side epilogues (idempotent max/min, gi!=gj
// guards the diagonal); fused last-block finalize.
__global__ __launch_bounds__(256) void gemm_reduce_kernel(
    const unsigned char* __restrict__ xq,
    const float* __restrict__ sq,
    const int* __restrict__ labels,
    unsigned int* __restrict__ ap,
    unsigned int* __restrict__ an,
    int* __restrict__ counter,
    float* __restrict__ out) {
    __shared__ __align__(16) unsigned char As[64 * BK];    // 16 KB
    __shared__ __align__(16) unsigned char Bs[128 * BK];   // 32 KB

    // XCD-aware bijective swizzle: 1056 = 8 * 132 exactly.
    const int orig = blockIdx.x;
    const int wgid = (orig & 7) * (NTILES / 8) + (orig >> 3);

    // decode tile: row-block mi64 (64 rows), col-block nj (128 cols),
    // tiles with 128*nj + 127 >= 64*mi64, i.e. nj >= floor(mi64/2).
    int rem = wgid;
    int mi64 = 0;
    while (rem >= 32 - (mi64 >> 1)) { rem -= 32 - (mi64 >> 1); ++mi64; }
    const int nj = (mi64 >> 1) + rem;
    const int row0 = mi64 * 64;
    const int col0 = nj * 128;

    const int t = threadIdx.x;
    const int lane = t & 63;
    const int wave = t >> 6;
    const int c = lane & 15;   // fragment column lane
    const int q = lane >> 4;   // k-quad
    const int wc = wave * 32;  // wave col offset (rows shared by all waves)

    i32x4 acc[4][2];
#pragma unroll
    for (int mi = 0; mi < 4; ++mi)
#pragma unroll
        for (int ni = 0; ni < 2; ++ni)
            acc[mi][ni] = (i32x4){0, 0, 0, 0};

    // Staging: rows are 256 B = 16 chunks of 16 B. A tile 64 rows = 1024
    // chunks (4/thread), B tile 128 rows = 2048 chunks (8/thread).
    // Chunk ci = t + 256*s: row = ci>>4 = (t>>4) + 16*s, col = t&15;
    // source col XOR-swizzled: col ^ (row&15), and row&15 = (t>>4)&15 is
    // s-invariant, so one swizzled col per thread.
    const int rowb = t >> 4;
    const int colsw = (t & 15) ^ (rowb & 15);
    const unsigned char* gA[4];
    const unsigned char* gB[8];
#pragma unroll
    for (int s = 0; s < 4; ++s)
        gA[s] = xq + (size_t)(row0 + rowb + 16 * s) * DD + colsw * 16;
#pragma unroll
    for (int s = 0; s < 8; ++s)
        gB[s] = xq + (size_t)(col0 + rowb + 16 * s) * DD + colsw * 16;

    for (int it = 0; it < NIT; ++it) {
        const int k0 = it * BK;  // lock-step K (no stagger -> L2-resident slice)
#pragma unroll
        for (int s = 0; s < 4; ++s)
            __builtin_amdgcn_global_load_lds(
                (const __attribute__((address_space(1))) void*)(gA[s] + k0),
                (__attribute__((address_space(3))) void*)&As[(t + 256 * s) * 16],
                16, 0, 0);
#pragma unroll
        for (int s = 0; s < 8; ++s)
            __builtin_amdgcn_global_load_lds(
                (const __attribute__((address_space(1))) void*)(gB[s] + k0),
                (__attribute__((address_space(3))) void*)&Bs[(t + 256 * s) * 16],
                16, 0, 0);
        __syncthreads();

        const i32x4* Av = (const i32x4*)As;
        const i32x4* Bv = (const i32x4*)Bs;
#pragma unroll
        for (int ks = 0; ks < 4; ++ks) {
            const int kc = q + 4 * ks;  // k-chunk for this lane's fragment
            i32x4 af[4], bfr[2];
#pragma unroll
            for (int mi = 0; mi < 4; ++mi) {
                const int r = mi * 16 + c;
                af[mi] = Av[r * 16 + (kc ^ (r & 15))];
            }
#pragma unroll
            for (int ni = 0; ni < 2; ++ni) {
                const int r = wc + ni * 16 + c;
                bfr[ni] = Bv[r * 16 + (kc ^ (r & 15))];
            }
#pragma unroll
            for (int mi = 0; mi < 4; ++mi)
#pragma unroll
                for (int ni = 0; ni < 2; ++ni)
                    acc[mi][ni] = __builtin_amdgcn_mfma_i32_16x16x64_i8(
                        af[mi], bfr[ni], acc[mi][ni], 0, 0, 0);
        }
        __syncthreads();
    }

    // --- Epilogue ---
    // C/D layout 16x16: col = lane&15 (c), row = q*4 + reg [m89/m91;
    // dtype-independent m121-m128]
    float sq_col[2];
    int lab_col[2];
#pragma unroll
    for (int ni = 0; ni < 2; ++ni) {
        const int gj = col0 + wc + ni * 16 + c;
        sq_col[ni] = sq[gj];
        lab_col[ni] = labels[gj];
    }
    int lab_row[4][4];
    float dist[4][2][4];
#pragma unroll
    for (int mi = 0; mi < 4; ++mi) {
#pragma unroll
        for (int r = 0; r < 4; ++r) {
            const int gi = row0 + mi * 16 + q * 4 + r;
            const float sqi = sq[gi];
            lab_row[mi][r] = labels[gi];
#pragma unroll
            for (int ni = 0; ni < 2; ++ni) {
                float d2 = sqi + sq_col[ni] - C2 * (float)acc[mi][ni][r];
                dist[mi][ni][r] = sqrtf(fmaxf(d2, 0.0f));
            }
        }
    }

    // Row-side: rows gi vs this wave's 32 columns.
#pragma unroll
    for (int mi = 0; mi < 4; ++mi) {
#pragma unroll
        for (int r = 0; r < 4; ++r) {
            const int gi = row0 + mi * 16 + q * 4 + r;
            const int li = lab_row[mi][r];
            float apm = 0.0f;
            float anm = __builtin_inff();
#pragma unroll
            for (int ni = 0; ni < 2; ++ni) {
                const int gj = col0 + wc + ni * 16 + c;
                const float d = dist[mi][ni][r];
                if (li == lab_col[ni]) {
                    if (gi != gj) apm = fmaxf(apm, d);  // exclude diagonal
                } else {
                    anm = fminf(anm, d);
                }
            }
#pragma unroll
            for (int off = 1; off < 16; off <<= 1) {
                apm = fmaxf(apm, __shfl_xor(apm, off, 16));
                anm = fminf(anm, __shfl_xor(anm, off, 16));
            }
            if (c == 0) {
                atomicMax(&ap[gi], __float_as_uint(apm));
                atomicMin(&an[gi], __float_as_uint(anm));
            }
        }
    }

    // Column-side (transposed): S(gi,gj) also serves row gj (dupes
    // idempotent; diagonal guarded).
#pragma unroll
    for (int ni = 0; ni < 2; ++ni) {
        const int gj = col0 + wc + ni * 16 + c;
        const int lj = lab_col[ni];
        float apm = 0.0f;
        float anm = __builtin_inff();
#pragma unroll
        for (int mi = 0; mi < 4; ++mi) {
#pragma unroll
            for (int r = 0; r < 4; ++r) {
                const int gi = row0 + mi * 16 + q * 4 + r;
                const float d = dist[mi][ni][r];
                if (lj == lab_row[mi][r]) {
                    if (gi != gj) apm = fmaxf(apm, d);  // exclude diagonal
                } else {
                    anm = fminf(anm, d);
                }
            }
        }
        apm = fmaxf(apm, __shfl_xor(apm, 16, 64));
        anm = fminf(anm, __shfl_xor(anm, 16, 64));
        apm = fmaxf(apm, __shfl_xor(apm, 32, 64));
        anm = fminf(anm, __shfl_xor(anm, 32, 64));
        if (q == 0) {
            atomicMax(&ap[gj], __float_as_uint(apm));
            atomicMin(&an[gj], __float_as_uint(anm));
        }
    }

    // --- Fused finalize: last block to finish reduces the loss ---
    __syncthreads();  // drains this block's atomics before counter release
    int* flag = (int*)As;
    if (t == 0) {
        int old = __hip_atomic_fetch_add(counter, 1, __ATOMIC_ACQ_REL,
                                         __HIP_MEMORY_SCOPE_AGENT);
        flag[0] = (old == NTILES - 1) ? 1 : 0;
    }
    __syncthreads();
    if (flag[0]) {
        float sum = 0.0f;
        int cnt = 0;
        for (int i = t; i < NN; i += 256) {
            const float a = __uint_as_float(__hip_atomic_load(
                &ap[i], __ATOMIC_RELAXED, __HIP_MEMORY_SCOPE_AGENT));
            const float b = __uint_as_float(__hip_atomic_load(
                &an[i], __ATOMIC_RELAXED, __HIP_MEMORY_SCOPE_AGENT));
            if ((a > 0.0f) && (b < __builtin_inff())) {
                sum += fmaxf(a - b + MARGIN_F, 0.0f);
                cnt += 1;
            }
        }
        for (int off = 32; off > 0; off >>= 1) {
            sum += __shfl_down(sum, off, 64);
            cnt += __shfl_down(cnt, off, 64);
        }
        float* ssum = (float*)Bs;
        int* scnt = (int*)Bs + 8;
        if (lane == 0) { ssum[wave] = sum; scnt[wave] = cnt; }
        __syncthreads();
        if (t == 0) {
            float s = 0.0f; int n = 0;
#pragma unroll
            for (int w = 0; w < 4; ++w) { s += ssum[w]; n += scnt[w]; }
            out[0] = (n > 0) ? s / (float)n : 0.0f;
        }
    }
}

extern "C" void kernel_launch(void* const* d_in, const int* in_sizes, int n_in,
                              void* d_out, int out_size, void* d_ws, size_t ws_size,
                              hipStream_t stream) {
    const float* x = (const float*)d_in[0];
    const int* labels = (const int*)d_in[1];
    float* out = (float*)d_out;

    char* ws = (char*)d_ws;
    unsigned char* xq = (unsigned char*)ws;                         // 4096*2048 B
    float* sq = (float*)(ws + (size_t)NN * DD);
    unsigned int* ap = (unsigned int*)(ws + (size_t)NN * DD + (size_t)NN * 4);
    unsigned int* an = (unsigned int*)(ws + (size_t)NN * DD + (size_t)NN * 8);
    int* counter = (int*)(ws + (size_t)NN * DD + (size_t)NN * 12);

    prep_kernel<<<NN / 4, 256, 0, stream>>>(x, xq, sq, ap, an, counter);
    gemm_reduce_kernel<<<NTILES, 256, 0, stream>>>(xq, sq, labels, ap, an, counter, out);
}

// Round 6
// 143.133 us; speedup vs baseline: 1.0962x; 1.0646x over previous
//
#include <hip/hip_runtime.h>

#define NN 4096
#define DD 2048
#define MARGIN_F 0.3f
#define NTILES 1056  // 64x128 tiles covering the upper triangle (dupes OK)
#define BK 128       // K bytes per stage
#define NIT (DD / BK)  // 16
#define QS (127.0f / 6.0f)
#define C2 (2.0f * (6.0f / 127.0f) * (6.0f / 127.0f))  // 2/QS^2

typedef __attribute__((ext_vector_type(4))) int i32x4;

__device__ __forceinline__ unsigned q8(float v) {
    int i = __float2int_rn(v * QS);
    i = min(127, max(-127, i));
    return (unsigned)(i & 255);
}

// 1024 blocks x 4 waves; each wave quantizes one row (int8) + fp32
// sum-of-squares; init ap/an/counter.
__global__ __launch_bounds__(256) void prep_kernel(const float* __restrict__ x,
                                                   unsigned char* __restrict__ xq,
                                                   float* __restrict__ sq,
                                                   unsigned int* __restrict__ ap,
                                                   unsigned int* __restrict__ an,
                                                   int* __restrict__ counter) {
    const int wave = threadIdx.x >> 6, lane = threadIdx.x & 63;
    const int row = blockIdx.x * 4 + wave;
    const float* xr = x + (size_t)row * DD;
    unsigned int* orow = (unsigned int*)(xq + (size_t)row * DD);
    float s = 0.0f;
#pragma unroll
    for (int j = 0; j < 8; ++j) {
        float4 v = ((const float4*)xr)[j * 64 + lane];
        s += v.x * v.x + v.y * v.y + v.z * v.z + v.w * v.w;
        orow[j * 64 + lane] = q8(v.x) | (q8(v.y) << 8) | (q8(v.z) << 16) | (q8(v.w) << 24);
    }
    for (int off = 32; off > 0; off >>= 1) s += __shfl_down(s, off, 64);
    if (lane == 0) {
        sq[row] = s;
        ap[row] = 0u;            // hardest-positive max starts at 0
        an[row] = 0x7F800000u;   // +inf
    }
    if (threadIdx.x == 0 && blockIdx.x == 0) counter[0] = 0;
}

// Symmetric batch-hard GEMM, int8. R6 = R0 structure (proven 72 us:
// 64x128 tiles, natural dispatch order, K-stagger, plain drain barriers)
// with ONE mechanism changed: FULL-GRID CO-RESIDENCY.
//   BK 256->128 single-buffered: LDS 48->24 KB -> 6 blocks/CU capacity
//   vs 4.125 needed -> all 1056 blocks resident from launch. R0-R5
//   post-mortems: runtime tracks OccupancyPercent only (19%/72us best,
//   13%/90us worst); per-block ~7900 cyc/iter vs ~400 cyc work = 95%
//   stall, hidden only by cross-block overlap. Eliminating sequential
//   rounds quadruples the overlap workforce.
// K-stagger kept at R0's exact granularity: phase = (blockIdx&7)*2 ->
// 8 start offsets, 256-B aligned (both no-stagger variants lost ~10us:
// address decorrelation, not L2 locality, is its mechanism). No XCD
// swizzle (falsified in R5: all tiles co-resident -> no temporal
// locality to create; FETCH unchanged, time worse).
// LDS reads keep free 2-way bank aliasing at BK=128: swz = kc^(r&7),
// lanes c/c+8 share swz -> same bank-quad, 2 lanes/bank = free (m136).
// mfma_i32_16x16x64_i8, wave = 64 rows x 32 cols (4x2 frags), 2
// k-chunks/stage, 16 stages (totals identical to R0: 96 loads, 256
// MFMAs). Both-side epilogues (idempotent max/min, gi!=gj guards the
// diagonal); fused last-block finalize.
__global__ __launch_bounds__(256) void gemm_reduce_kernel(
    const unsigned char* __restrict__ xq,
    const float* __restrict__ sq,
    const int* __restrict__ labels,
    unsigned int* __restrict__ ap,
    unsigned int* __restrict__ an,
    int* __restrict__ counter,
    float* __restrict__ out) {
    __shared__ __align__(16) unsigned char As[64 * BK];    // 8 KB
    __shared__ __align__(16) unsigned char Bs[128 * BK];   // 16 KB

    // decode tile: row-block mi64 (64 rows), col-block nj (128 cols),
    // tiles with 128*nj + 127 >= 64*mi64, i.e. nj >= floor(mi64/2).
    int rem = blockIdx.x;
    int mi64 = 0;
    while (rem >= 32 - (mi64 >> 1)) { rem -= 32 - (mi64 >> 1); ++mi64; }
    const int nj = (mi64 >> 1) + rem;
    const int row0 = mi64 * 64;
    const int col0 = nj * 128;
    const int phase = (blockIdx.x & 7) * 2;  // K-start stagger, 256-B granule

    const int t = threadIdx.x;
    const int lane = t & 63;
    const int wave = t >> 6;
    const int c = lane & 15;   // fragment column lane
    const int q = lane >> 4;   // k-quad
    const int wc = wave * 32;  // wave col offset (rows shared by all waves)

    i32x4 acc[4][2];
#pragma unroll
    for (int mi = 0; mi < 4; ++mi)
#pragma unroll
        for (int ni = 0; ni < 2; ++ni)
            acc[mi][ni] = (i32x4){0, 0, 0, 0};

    // Staging: rows are 128 B = 8 chunks of 16 B. A tile 64 rows = 512
    // chunks (2/thread), B tile 128 rows = 1024 chunks (4/thread).
    // Chunk ci = t + 256*s: row = ci>>3 = (t>>3) + 32*s, col = t&7;
    // source col XOR-swizzled: col ^ (row&7), and row&7 = (t>>3)&7 is
    // s-invariant, so one swizzled col per thread.
    const int rowb = t >> 3;
    const int colsw = (t & 7) ^ (rowb & 7);
    const unsigned char* gA[2];
    const unsigned char* gB[4];
#pragma unroll
    for (int s = 0; s < 2; ++s)
        gA[s] = xq + (size_t)(row0 + rowb + 32 * s) * DD + colsw * 16;
#pragma unroll
    for (int s = 0; s < 4; ++s)
        gB[s] = xq + (size_t)(col0 + rowb + 32 * s) * DD + colsw * 16;

    for (int it = 0; it < NIT; ++it) {
        const int k0 = ((it + phase) & (NIT - 1)) * BK;
#pragma unroll
        for (int s = 0; s < 2; ++s)
            __builtin_amdgcn_global_load_lds(
                (const __attribute__((address_space(1))) void*)(gA[s] + k0),
                (__attribute__((address_space(3))) void*)&As[(t + 256 * s) * 16],
                16, 0, 0);
#pragma unroll
        for (int s = 0; s < 4; ++s)
            __builtin_amdgcn_global_load_lds(
                (const __attribute__((address_space(1))) void*)(gB[s] + k0),
                (__attribute__((address_space(3))) void*)&Bs[(t + 256 * s) * 16],
                16, 0, 0);
        __syncthreads();

        const i32x4* Av = (const i32x4*)As;
        const i32x4* Bv = (const i32x4*)Bs;
#pragma unroll
        for (int ks = 0; ks < 2; ++ks) {
            const int kc = q + 4 * ks;  // k-chunk for this lane's fragment
            i32x4 af[4], bfr[2];
#pragma unroll
            for (int mi = 0; mi < 4; ++mi) {
                const int r = mi * 16 + c;
                af[mi] = Av[r * 8 + (kc ^ (r & 7))];
            }
#pragma unroll
            for (int ni = 0; ni < 2; ++ni) {
                const int r = wc + ni * 16 + c;
                bfr[ni] = Bv[r * 8 + (kc ^ (r & 7))];
            }
#pragma unroll
            for (int mi = 0; mi < 4; ++mi)
#pragma unroll
                for (int ni = 0; ni < 2; ++ni)
                    acc[mi][ni] = __builtin_amdgcn_mfma_i32_16x16x64_i8(
                        af[mi], bfr[ni], acc[mi][ni], 0, 0, 0);
        }
        __syncthreads();
    }

    // --- Epilogue ---
    // C/D layout 16x16: col = lane&15 (c), row = q*4 + reg [m89/m91;
    // dtype-independent m121-m128]
    float sq_col[2];
    int lab_col[2];
#pragma unroll
    for (int ni = 0; ni < 2; ++ni) {
        const int gj = col0 + wc + ni * 16 + c;
        sq_col[ni] = sq[gj];
        lab_col[ni] = labels[gj];
    }
    int lab_row[4][4];
    float dist[4][2][4];
#pragma unroll
    for (int mi = 0; mi < 4; ++mi) {
#pragma unroll
        for (int r = 0; r < 4; ++r) {
            const int gi = row0 + mi * 16 + q * 4 + r;
            const float sqi = sq[gi];
            lab_row[mi][r] = labels[gi];
#pragma unroll
            for (int ni = 0; ni < 2; ++ni) {
                float d2 = sqi + sq_col[ni] - C2 * (float)acc[mi][ni][r];
                dist[mi][ni][r] = sqrtf(fmaxf(d2, 0.0f));
            }
        }
    }

    // Row-side: rows gi vs this wave's 32 columns.
#pragma unroll
    for (int mi = 0; mi < 4; ++mi) {
#pragma unroll
        for (int r = 0; r < 4; ++r) {
            const int gi = row0 + mi * 16 + q * 4 + r;
            const int li = lab_row[mi][r];
            float apm = 0.0f;
            float anm = __builtin_inff();
#pragma unroll
            for (int ni = 0; ni < 2; ++ni) {
                const int gj = col0 + wc + ni * 16 + c;
                const float d = dist[mi][ni][r];
                if (li == lab_col[ni]) {
                    if (gi != gj) apm = fmaxf(apm, d);  // exclude diagonal
                } else {
                    anm = fminf(anm, d);
                }
            }
#pragma unroll
            for (int off = 1; off < 16; off <<= 1) {
                apm = fmaxf(apm, __shfl_xor(apm, off, 16));
                anm = fminf(anm, __shfl_xor(anm, off, 16));
            }
            if (c == 0) {
                atomicMax(&ap[gi], __float_as_uint(apm));
                atomicMin(&an[gi], __float_as_uint(anm));
            }
        }
    }

    // Column-side (transposed): S(gi,gj) also serves row gj (dupes
    // idempotent; diagonal guarded).
#pragma unroll
    for (int ni = 0; ni < 2; ++ni) {
        const int gj = col0 + wc + ni * 16 + c;
        const int lj = lab_col[ni];
        float apm = 0.0f;
        float anm = __builtin_inff();
#pragma unroll
        for (int mi = 0; mi < 4; ++mi) {
#pragma unroll
            for (int r = 0; r < 4; ++r) {
                const int gi = row0 + mi * 16 + q * 4 + r;
                const float d = dist[mi][ni][r];
                if (lj == lab_row[mi][r]) {
                    if (gi != gj) apm = fmaxf(apm, d);  // exclude diagonal
                } else {
                    anm = fminf(anm, d);
                }
            }
        }
        apm = fmaxf(apm, __shfl_xor(apm, 16, 64));
        anm = fminf(anm, __shfl_xor(anm, 16, 64));
        apm = fmaxf(apm, __shfl_xor(apm, 32, 64));
        anm = fminf(anm, __shfl_xor(anm, 32, 64));
        if (q == 0) {
            atomicMax(&ap[gj], __float_as_uint(apm));
            atomicMin(&an[gj], __float_as_uint(anm));
        }
    }

    // --- Fused finalize: last block to finish reduces the loss ---
    __syncthreads();  // drains this block's atomics before counter release
    int* flag = (int*)As;
    if (t == 0) {
        int old = __hip_atomic_fetch_add(counter, 1, __ATOMIC_ACQ_REL,
                                         __HIP_MEMORY_SCOPE_AGENT);
        flag[0] = (old == NTILES - 1) ? 1 : 0;
    }
    __syncthreads();
    if (flag[0]) {
        float sum = 0.0f;
        int cnt = 0;
        for (int i = t; i < NN; i += 256) {
            const float a = __uint_as_float(__hip_atomic_load(
                &ap[i], __ATOMIC_RELAXED, __HIP_MEMORY_SCOPE_AGENT));
            const float b = __uint_as_float(__hip_atomic_load(
                &an[i], __ATOMIC_RELAXED, __HIP_MEMORY_SCOPE_AGENT));
            if ((a > 0.0f) && (b < __builtin_inff())) {
                sum += fmaxf(a - b + MARGIN_F, 0.0f);
                cnt += 1;
            }
        }
        for (int off = 32; off > 0; off >>= 1) {
            sum += __shfl_down(sum, off, 64);
            cnt += __shfl_down(cnt, off, 64);
        }
        float* ssum = (float*)Bs;
        int* scnt = (int*)Bs + 8;
        if (lane == 0) { ssum[wave] = sum; scnt[wave] = cnt; }
        __syncthreads();
        if (t == 0) {
            float s = 0.0f; int n = 0;
#pragma unroll
            for (int w = 0; w < 4; ++w) { s += ssum[w]; n += scnt[w]; }
            out[0] = (n > 0) ? s / (float)n : 0.0f;
        }
    }
}

extern "C" void kernel_launch(void* const* d_in, const int* in_sizes, int n_in,
                              void* d_out, int out_size, void* d_ws, size_t ws_size,
                              hipStream_t stream) {
    const float* x = (const float*)d_in[0];
    const int* labels = (const int*)d_in[1];
    float* out = (float*)d_out;

    char* ws = (char*)d_ws;
    unsigned char* xq = (unsigned char*)ws;                         // 4096*2048 B
    float* sq = (float*)(ws + (size_t)NN * DD);
    unsigned int* ap = (unsigned int*)(ws + (size_t)NN * DD + (size_t)NN * 4);
    unsigned int* an = (unsigned int*)(ws + (size_t)NN * DD + (size_t)NN * 8);
    int* counter = (int*)(ws + (size_t)NN * DD + (size_t)NN * 12);

    prep_kernel<<<NN / 4, 256, 0, stream>>>(x, xq, sq, ap, an, counter);
    gemm_reduce_kernel<<<NTILES, 256, 0, stream>>>(xq, sq, labels, ap, an, counter, out);
}